// Round 1
// baseline (20.376 us; speedup 1.0000x reference)
//
#include <hip/hip_runtime.h>

#define HH 224
#define WW 224
#define K 15
#define PAD 7
#define BX 32
#define BY 8
#define TW (BX + K - 1)   /* 46 */
#define TH (BY + K - 1)   /* 22 */
#define TSTRIDE 48        /* pad to 48: row-to-row bank shift = 16 -> 2-way (free) */

__global__ __launch_bounds__(BX * BY)
void bilateral_denoise_kernel(const float* __restrict__ x,
                              const float* __restrict__ blur_sigma_p,
                              const float* __restrict__ diff_sigma_p,
                              float* __restrict__ out)
{
    __shared__ float tile[TH * TSTRIDE];

    const int tx = threadIdx.x;           // 0..31
    const int ty = threadIdx.y;           // 0..7
    const int tid = ty * BX + tx;
    const int w0 = blockIdx.x * BX;
    const int h0 = blockIdx.y * BY;
    const int plane = blockIdx.z;         // b*C + c, 0..5

    const float* __restrict__ xp = x + (size_t)plane * HH * WW;

    // ---- stage halo tile (boundary -> -100, matching constant pad) ----
    for (int idx = tid; idx < TH * TW; idx += BX * BY) {
        const int r = idx / TW;
        const int c = idx - r * TW;
        const int gh = h0 - PAD + r;
        const int gw = w0 - PAD + c;
        float v = -100.0f;
        if (gh >= 0 && gh < HH && gw >= 0 && gw < WW) v = xp[gh * WW + gw];
        tile[r * TSTRIDE + c] = v;
    }
    __syncthreads();

    const float bs = blur_sigma_p[0];
    const float ds = diff_sigma_p[0];
    const float LOG2E = 1.44269504088896340736f;
    const float na  = -LOG2E / (ds * ds);   // scale on d^2
    const float nk2 = -LOG2E / (bs * bs);   // scale on spatial dist

    // per-column spatial terms (compile-time dist constants under unroll)
    float nbj[K];
#pragma unroll
    for (int j = 0; j < K; ++j) {
        nbj[j] = (float)((j - PAD) * (j - PAD)) * nk2;
    }

    const float cv = tile[(ty + PAD) * TSTRIDE + tx + PAD];

    float wsum = 0.0f;
    float vsum = 0.0f;

#pragma unroll
    for (int i = 0; i < K; ++i) {
        const float nbi = (float)((i - PAD) * (i - PAD)) * nk2;
        const float* __restrict__ row = &tile[(ty + i) * TSTRIDE + tx];
#pragma unroll
        for (int j = 0; j < K; ++j) {
            const float v = row[j];
            const float d = v - cv;
            const float m = d * na;
            const float t = __builtin_fmaf(m, d, nbi + nbj[j]);  // -(d^2/ds^2 + dist/bs^2)*log2e
            const float e = __builtin_amdgcn_exp2f(t);
            wsum += e;
            vsum = __builtin_fmaf(e, v, vsum);
        }
    }

    out[(size_t)plane * HH * WW + (size_t)(h0 + ty) * WW + (w0 + tx)] = vsum / wsum;
}

extern "C" void kernel_launch(void* const* d_in, const int* in_sizes, int n_in,
                              void* d_out, int out_size, void* d_ws, size_t ws_size,
                              hipStream_t stream) {
    const float* x  = (const float*)d_in[0];
    const float* bs = (const float*)d_in[1];
    const float* ds = (const float*)d_in[2];
    float* out = (float*)d_out;

    const int planes = in_sizes[0] / (HH * WW);   // B*C = 6
    dim3 grid(WW / BX, HH / BY, planes);          // 7 x 28 x 6 = 1176 blocks
    dim3 block(BX, BY, 1);
    hipLaunchKernelGGL(bilateral_denoise_kernel, grid, block, 0, stream,
                       x, bs, ds, out);
}

// Round 2
// 20.346 us; speedup vs baseline: 1.0015x; 1.0015x over previous
//
#include <hip/hip_runtime.h>

#define HH 224
#define WW 224
#define K 15
#define PAD 7
#define BX 32
#define BY 8
#define TW (BX + K - 1)   /* 46 */
#define TH (BY + K - 1)   /* 22 */
#define TSTRIDE 48        /* row-to-row bank shift = 16 -> 2-way aliasing (free, m136) */

__global__ __launch_bounds__(BX * BY)
void bilateral_denoise_kernel(const float* __restrict__ x,
                              const float* __restrict__ blur_sigma_p,
                              const float* __restrict__ diff_sigma_p,
                              float* __restrict__ out)
{
    __shared__ float tile[TH * TSTRIDE];

    const int tx = threadIdx.x;           // 0..31
    const int ty = threadIdx.y;           // 0..7
    const int tid = ty * BX + tx;
    const int w0 = blockIdx.x * BX;
    const int h0 = blockIdx.y * BY;
    const int plane = blockIdx.z;         // b*C + c, 0..5

    const float* __restrict__ xp = x + (size_t)plane * HH * WW;

    // ---- stage halo tile (boundary -> -100, matching constant pad) ----
    for (int idx = tid; idx < TH * TW; idx += BX * BY) {
        const int r = idx / TW;
        const int c = idx - r * TW;
        const int gh = h0 - PAD + r;
        const int gw = w0 - PAD + c;
        float v = -100.0f;
        if (gh >= 0 && gh < HH && gw >= 0 && gw < WW) v = xp[gh * WW + gw];
        tile[r * TSTRIDE + c] = v;
    }
    __syncthreads();

    const float bs = blur_sigma_p[0];
    const float ds = diff_sigma_p[0];
    const float LOG2E = 1.44269504088896340736f;
    const float na  = -LOG2E / (ds * ds);   // scale on (v-cv)^2
    const float nk2 = -LOG2E / (bs * bs);   // scale on spatial squared distance

    const float cv = tile[(ty + PAD) * TSTRIDE + tx + PAD];
    // na*(v-cv)^2 = na*v^2 + bb*v + cc
    const float bb = -2.0f * na * cv;
    const float cc = na * cv * cv;

    // per-column accumulators: spatial column weight applied in the finale
    float colw[K];
    float colv[K];
#pragma unroll
    for (int j = 0; j < K; ++j) { colw[j] = 0.0f; colv[j] = 0.0f; }

#pragma unroll
    for (int i = 0; i < K; ++i) {
        // fold the row spatial term into the constant: ci = cc + (i-PAD)^2 * nk2
        const float ci = __builtin_fmaf((float)((i - PAD) * (i - PAD)), nk2, cc);
        const float* __restrict__ row = &tile[(ty + i) * TSTRIDE + tx];
#pragma unroll
        for (int j = 0; j < K; ++j) {
            const float v = row[j];
            const float inner = __builtin_fmaf(v, na, bb);     // na*v + bb
            const float t = __builtin_fmaf(v, inner, ci);      // na*v^2 + bb*v + ci
            const float e = __builtin_amdgcn_exp2f(t);         // range * row-spatial weight
            colw[j] += e;
            colv[j] = __builtin_fmaf(e, v, colv[j]);
        }
    }

    // finale: apply column spatial weights wj = exp2(nk2*(j-PAD)^2)
    float wsum = 0.0f;
    float vsum = 0.0f;
#pragma unroll
    for (int j = 0; j < K; ++j) {
        const float wj = __builtin_amdgcn_exp2f((float)((j - PAD) * (j - PAD)) * nk2);
        wsum = __builtin_fmaf(wj, colw[j], wsum);
        vsum = __builtin_fmaf(wj, colv[j], vsum);
    }

    out[(size_t)plane * HH * WW + (size_t)(h0 + ty) * WW + (w0 + tx)] = vsum / wsum;
}

extern "C" void kernel_launch(void* const* d_in, const int* in_sizes, int n_in,
                              void* d_out, int out_size, void* d_ws, size_t ws_size,
                              hipStream_t stream) {
    const float* x  = (const float*)d_in[0];
    const float* bs = (const float*)d_in[1];
    const float* ds = (const float*)d_in[2];
    float* out = (float*)d_out;

    const int planes = in_sizes[0] / (HH * WW);   // B*C = 6
    dim3 grid(WW / BX, HH / BY, planes);          // 7 x 28 x 6 = 1176 blocks
    dim3 block(BX, BY, 1);
    hipLaunchKernelGGL(bilateral_denoise_kernel, grid, block, 0, stream,
                       x, bs, ds, out);
}